// Round 1
// baseline (1687.471 us; speedup 1.0000x reference)
//
#include <hip/hip_runtime.h>
#include <cstdint>

typedef __attribute__((ext_vector_type(8))) short short8;
typedef __attribute__((ext_vector_type(4))) float f32x4;

__device__ __forceinline__ unsigned short f2bf(float f) {
  unsigned int u = __float_as_uint(f);
  u += 0x7FFFu + ((u >> 16) & 1u);
  return (unsigned short)(u >> 16);
}

__device__ __forceinline__ void gload16(const void* g, void* l) {
  __builtin_amdgcn_global_load_lds((const __attribute__((address_space(1))) void*)g,
                                   (__attribute__((address_space(3))) void*)l,
                                   16, 0, 0);
}

__device__ __forceinline__ f32x4 mfma16(short8 a, short8 b, f32x4 c) {
  return __builtin_amdgcn_mfma_f32_16x16x32_bf16(a, b, c, 0, 0, 0);
}

__device__ __forceinline__ float gelu_f(float x) {
  float u = 0.7978845608028654f * x * (1.0f + 0.044715f * x * x);
  u = fminf(fmaxf(u, -20.f), 20.f);
  float e = __expf(2.f * u);
  return 0.5f * x * (1.f + (e - 1.f) / (e + 1.f));
}

// ---------------- fp32 -> bf16 convert ----------------
__global__ void cvt_kernel(const float* __restrict__ src, unsigned short* __restrict__ dst, long n8) {
  long i = (long)blockIdx.x * blockDim.x + threadIdx.x;
  long stride = (long)gridDim.x * blockDim.x;
  for (; i < n8; i += stride) {
    float4 f0 = ((const float4*)src)[2*i];
    float4 f1 = ((const float4*)src)[2*i+1];
    unsigned int p[4];
    p[0] = (unsigned int)f2bf(f0.x) | ((unsigned int)f2bf(f0.y) << 16);
    p[1] = (unsigned int)f2bf(f0.z) | ((unsigned int)f2bf(f0.w) << 16);
    p[2] = (unsigned int)f2bf(f1.x) | ((unsigned int)f2bf(f1.y) << 16);
    p[3] = (unsigned int)f2bf(f1.z) | ((unsigned int)f2bf(f1.w) << 16);
    ((uint4*)dst)[i] = *(uint4*)p;
  }
}

// ---------------- LN (fp32 in) -> bf16 out ----------------
__global__ void ln_kernel(const float* __restrict__ in, const float* __restrict__ g,
                          const float* __restrict__ bb, unsigned short* __restrict__ out) {
  __shared__ float redA[4], redB[4];
  const int tid = threadIdx.x;
  const int lane = tid & 63, wv = tid >> 6;
  const long base = (long)blockIdx.x * 2048 + tid * 8;
  const int c = tid * 8;
  float x[8];
  *(float4*)(x)     = *(const float4*)(in + base);
  *(float4*)(x + 4) = *(const float4*)(in + base + 4);
  float s = 0.f, ss = 0.f;
#pragma unroll
  for (int j = 0; j < 8; ++j) { s += x[j]; ss += x[j]*x[j]; }
#pragma unroll
  for (int k = 1; k < 64; k <<= 1) { s += __shfl_xor(s, k); ss += __shfl_xor(ss, k); }
  if (lane == 0) { redA[wv] = s; redB[wv] = ss; }
  __syncthreads();
  s  = redA[0] + redA[1] + redA[2] + redA[3];
  ss = redB[0] + redB[1] + redB[2] + redB[3];
  float mean = s * (1.f/2048.f);
  float var  = ss * (1.f/2048.f) - mean*mean;
  float rr = rsqrtf(var + 1e-5f);
  unsigned int po[4];
#pragma unroll
  for (int j = 0; j < 4; ++j) {
    float e0 = (x[2*j]   - mean) * rr * g[c+2*j]   + bb[c+2*j];
    float e1 = (x[2*j+1] - mean) * rr * g[c+2*j+1] + bb[c+2*j+1];
    po[j] = (unsigned int)f2bf(e0) | ((unsigned int)f2bf(e1) << 16);
  }
  *(uint4*)(out + base) = *(uint4*)po;
}

// ---------------- dense_out -> LN_s1 -> +h -> h2 ; LN_post(h2) -> y0(bf16) ----------------
__global__ void fuse1_kernel(const float* __restrict__ dn, const float* __restrict__ hin,
                             const float* __restrict__ g1, const float* __restrict__ b1,
                             const float* __restrict__ g2, const float* __restrict__ b2,
                             float* __restrict__ h2o, unsigned short* __restrict__ y0o) {
  __shared__ float redA[4], redB[4];
  const int tid = threadIdx.x;
  const int lane = tid & 63, wv = tid >> 6;
  const long base = (long)blockIdx.x * 2048 + tid * 8;
  const int c = tid * 8;
  float d[8], h[8];
  *(float4*)(d)     = *(const float4*)(dn + base);
  *(float4*)(d + 4) = *(const float4*)(dn + base + 4);
  *(float4*)(h)     = *(const float4*)(hin + base);
  *(float4*)(h + 4) = *(const float4*)(hin + base + 4);
  float s = 0.f, ss = 0.f;
#pragma unroll
  for (int j = 0; j < 8; ++j) { s += d[j]; ss += d[j]*d[j]; }
#pragma unroll
  for (int k = 1; k < 64; k <<= 1) { s += __shfl_xor(s, k); ss += __shfl_xor(ss, k); }
  if (lane == 0) { redA[wv] = s; redB[wv] = ss; }
  __syncthreads();
  s  = redA[0] + redA[1] + redA[2] + redA[3];
  ss = redB[0] + redB[1] + redB[2] + redB[3];
  float mean = s * (1.f/2048.f);
  float var  = ss * (1.f/2048.f) - mean*mean;
  float rr = rsqrtf(var + 1e-5f);
  float h2[8];
  float s2 = 0.f, ss2 = 0.f;
#pragma unroll
  for (int j = 0; j < 8; ++j) {
    float a = (d[j] - mean) * rr * g1[c+j] + b1[c+j];
    h2[j] = h[j] + a;
    s2 += h2[j]; ss2 += h2[j]*h2[j];
  }
  *(float4*)(h2o + base)     = *(float4*)(h2);
  *(float4*)(h2o + base + 4) = *(float4*)(h2 + 4);
#pragma unroll
  for (int k = 1; k < 64; k <<= 1) { s2 += __shfl_xor(s2, k); ss2 += __shfl_xor(ss2, k); }
  __syncthreads();
  if (lane == 0) { redA[wv] = s2; redB[wv] = ss2; }
  __syncthreads();
  s2  = redA[0] + redA[1] + redA[2] + redA[3];
  ss2 = redB[0] + redB[1] + redB[2] + redB[3];
  float mean2 = s2 * (1.f/2048.f);
  float var2  = ss2 * (1.f/2048.f) - mean2*mean2;
  float rr2 = rsqrtf(var2 + 1e-5f);
  unsigned int po[4];
#pragma unroll
  for (int j = 0; j < 4; ++j) {
    float e0 = (h2[2*j]   - mean2) * rr2 * g2[c+2*j]   + b2[c+2*j];
    float e1 = (h2[2*j+1] - mean2) * rr2 * g2[c+2*j+1] + b2[c+2*j+1];
    po[j] = (unsigned int)f2bf(e0) | ((unsigned int)f2bf(e1) << 16);
  }
  *(uint4*)(y0o + base) = *(uint4*)po;
}

// ---------------- out = h2 + LN_s2(y) ----------------
__global__ void fuse2_kernel(const float* __restrict__ y, const float* __restrict__ h2,
                             const float* __restrict__ g, const float* __restrict__ bb,
                             float* __restrict__ out) {
  __shared__ float redA[4], redB[4];
  const int tid = threadIdx.x;
  const int lane = tid & 63, wv = tid >> 6;
  const long base = (long)blockIdx.x * 2048 + tid * 8;
  const int c = tid * 8;
  float x[8], h[8];
  *(float4*)(x)     = *(const float4*)(y + base);
  *(float4*)(x + 4) = *(const float4*)(y + base + 4);
  *(float4*)(h)     = *(const float4*)(h2 + base);
  *(float4*)(h + 4) = *(const float4*)(h2 + base + 4);
  float s = 0.f, ss = 0.f;
#pragma unroll
  for (int j = 0; j < 8; ++j) { s += x[j]; ss += x[j]*x[j]; }
#pragma unroll
  for (int k = 1; k < 64; k <<= 1) { s += __shfl_xor(s, k); ss += __shfl_xor(ss, k); }
  if (lane == 0) { redA[wv] = s; redB[wv] = ss; }
  __syncthreads();
  s  = redA[0] + redA[1] + redA[2] + redA[3];
  ss = redB[0] + redB[1] + redB[2] + redB[3];
  float mean = s * (1.f/2048.f);
  float var  = ss * (1.f/2048.f) - mean*mean;
  float rr = rsqrtf(var + 1e-5f);
  float o[8];
#pragma unroll
  for (int j = 0; j < 8; ++j)
    o[j] = h[j] + (x[j] - mean) * rr * g[c+j] + bb[c+j];
  *(float4*)(out + base)     = *(float4*)(o);
  *(float4*)(out + base + 4) = *(float4*)(o + 4);
}

// ---------------- V transpose: qkv[tok][4096+h*128+d] -> vt[bh][d][s] ----------------
__global__ void vtrans_kernel(const unsigned short* __restrict__ qkv,
                              unsigned short* __restrict__ vt) {
  __shared__ unsigned short t[32][33];
  const int tid = threadIdx.x;
  const int s0 = blockIdx.x * 32;
  const int d0 = blockIdx.y * 32;
  const int bh = blockIdx.z;
  const int b = bh >> 4, h = bh & 15;
  const unsigned short* src = qkv + (long)b*1024*6144 + 4096 + h*128 + d0;
#pragma unroll
  for (int i = 0; i < 4; ++i) {
    int idx = i*256 + tid;
    int rs = idx >> 5, cd = idx & 31;
    t[rs][cd] = src[(long)(s0 + rs)*6144 + cd];
  }
  __syncthreads();
  unsigned short* dst = vt + ((long)bh*128 + d0)*1024 + s0;
#pragma unroll
  for (int i = 0; i < 4; ++i) {
    int idx = i*256 + tid;
    int rd = idx >> 5, cs = idx & 31;
    dst[(long)rd*1024 + cs] = t[cs][rd];
  }
}

// ---------------- bf16 GEMM: C[M,N] = A[M,K] @ B[N,K]^T + bias ----------------
template<int GELU, int OUTBF>
__global__ void gemm_bt(const unsigned short* __restrict__ A,
                        const unsigned short* __restrict__ Bm,
                        const float* __restrict__ bias,
                        void* __restrict__ C,
                        int M, int N, int K) {
  __shared__ unsigned short As[128*64];
  __shared__ unsigned short Bs[128*64];
  const int tid = threadIdx.x;
  const int lane = tid & 63;
  const int wv = tid >> 6;
  const int wr = wv >> 1, wc = wv & 1;
  const int wbase = tid & ~63;
  const long m0 = (long)blockIdx.y * 128;
  const long n0 = (long)blockIdx.x * 128;

  f32x4 acc[4][4];
#pragma unroll
  for (int i = 0; i < 4; ++i)
#pragma unroll
    for (int j = 0; j < 4; ++j) acc[i][j] = f32x4{0.f,0.f,0.f,0.f};

  for (int k0 = 0; k0 < K; k0 += 64) {
    __syncthreads();
#pragma unroll
    for (int i = 0; i < 4; ++i) {
      int c = i*256 + tid;
      int row = c >> 3;
      int cg = (c & 7) ^ (row & 7);             // swizzled source chunk
      const unsigned short* ga = A  + (m0 + row) * (long)K + k0 + cg*8;
      const unsigned short* gb = Bm + (n0 + row) * (long)K + k0 + cg*8;
      gload16(ga, As + (i*256 + wbase)*8);
      gload16(gb, Bs + (i*256 + wbase)*8);
    }
    __syncthreads();
#pragma unroll
    for (int ks = 0; ks < 2; ++ks) {
      const int kb = ks*4 + (lane >> 4);
      short8 av[4], bv[4];
#pragma unroll
      for (int m = 0; m < 4; ++m) {
        int r = wr*64 + m*16 + (lane & 15);
        av[m] = *(const short8*)(As + r*64 + ((kb ^ (r & 7)) << 3));
      }
#pragma unroll
      for (int n = 0; n < 4; ++n) {
        int r = wc*64 + n*16 + (lane & 15);
        bv[n] = *(const short8*)(Bs + r*64 + ((kb ^ (r & 7)) << 3));
      }
#pragma unroll
      for (int m = 0; m < 4; ++m)
#pragma unroll
        for (int n = 0; n < 4; ++n)
          acc[m][n] = mfma16(av[m], bv[n], acc[m][n]);
    }
  }
#pragma unroll
  for (int m = 0; m < 4; ++m) {
    long rbase = m0 + wr*64 + m*16 + ((lane >> 4) << 2);
#pragma unroll
    for (int n = 0; n < 4; ++n) {
      long col = n0 + wc*64 + n*16 + (lane & 15);
      float bvv = bias[col];
#pragma unroll
      for (int r4 = 0; r4 < 4; ++r4) {
        float v = acc[m][n][r4] + bvv;
        if (GELU) v = gelu_f(v);
        if (OUTBF) ((unsigned short*)C)[(rbase + r4) * (long)N + col] = f2bf(v);
        else       ((float*)C)[(rbase + r4) * (long)N + col] = v;
      }
    }
  }
}

// ---------------- flash attention (causal), bf16 ----------------
__global__ void attn_kernel(const unsigned short* __restrict__ qkv,
                            const unsigned short* __restrict__ vt,
                            unsigned short* __restrict__ ctx) {
  __shared__ unsigned short Qs[64*128];
  __shared__ unsigned short Ks[64*128];
  __shared__ unsigned short Vs[128*64];
  __shared__ unsigned short Ps[64*64];
  const int tid = threadIdx.x;
  const int lane = tid & 63;
  const int wv = tid >> 6;
  const int wbase = tid & ~63;
  const int qt = blockIdx.x;
  const int bh = blockIdx.y;
  const int b = bh >> 4, h = bh & 15;
  const unsigned short* Qg = qkv + (long)b*1024*6144 + h*128;
  const unsigned short* Kg = Qg + 2048;
  const unsigned short* Vg = vt + (long)bh*128*1024;

#pragma unroll
  for (int i = 0; i < 4; ++i) {           // stage Q tile (64 x 128)
    int c = i*256 + tid;
    int row = c >> 4;
    int cg = c & 15;
    int cl = (cg & 8) | ((cg & 7) ^ (row & 7));
    gload16(Qg + (long)(qt*64 + row)*6144 + cl*8, Qs + (i*256 + wbase)*8);
  }

  f32x4 o[8];
#pragma unroll
  for (int i = 0; i < 8; ++i) o[i] = f32x4{0.f,0.f,0.f,0.f};
  float mrow[4] = {-1e30f,-1e30f,-1e30f,-1e30f};
  float lrow[4] = {0.f,0.f,0.f,0.f};

  const int nkv = qt + 1;
  for (int kt = 0; kt < nkv; ++kt) {
    __syncthreads();
#pragma unroll
    for (int i = 0; i < 4; ++i) {         // stage K (64x128) and V^T (128x64)
      int c = i*256 + tid;
      int row = c >> 4;
      int cg = c & 15;
      int cl = (cg & 8) | ((cg & 7) ^ (row & 7));
      gload16(Kg + (long)(kt*64 + row)*6144 + cl*8, Ks + (i*256 + wbase)*8);
      int rv = c >> 3;
      int cvv = (c & 7) ^ (rv & 7);
      gload16(Vg + (long)rv*1024 + kt*64 + cvv*8, Vs + (i*256 + wbase)*8);
    }
    __syncthreads();

    f32x4 s[4];
#pragma unroll
    for (int n = 0; n < 4; ++n) s[n] = f32x4{0.f,0.f,0.f,0.f};
#pragma unroll
    for (int ks = 0; ks < 4; ++ks) {
      int kb = ks*4 + (lane >> 4);
      int rq = wv*16 + (lane & 15);
      short8 aq = *(const short8*)(Qs + rq*128 + (((kb & 8) | ((kb & 7) ^ (rq & 7))) << 3));
#pragma unroll
      for (int n = 0; n < 4; ++n) {
        int rk = n*16 + (lane & 15);
        short8 bk = *(const short8*)(Ks + rk*128 + (((kb & 8) | ((kb & 7) ^ (rk & 7))) << 3));
        s[n] = mfma16(aq, bk, s[n]);
      }
    }
    const float sc = 0.08838834764831845f;
#pragma unroll
    for (int n = 0; n < 4; ++n)
#pragma unroll
      for (int r = 0; r < 4; ++r) s[n][r] *= sc;
    if (kt == qt) {
#pragma unroll
      for (int n = 0; n < 4; ++n) {
        int tcol = kt*64 + n*16 + (lane & 15);
#pragma unroll
        for (int r = 0; r < 4; ++r) {
          int qrow = qt*64 + wv*16 + ((lane >> 4) << 2) + r;
          if (tcol > qrow) s[n][r] = -1e30f;
        }
      }
    }
    float pm[4], sf[4], rs[4];
#pragma unroll
    for (int r = 0; r < 4; ++r) {
      float m = fmaxf(fmaxf(s[0][r], s[1][r]), fmaxf(s[2][r], s[3][r]));
#pragma unroll
      for (int k = 1; k < 16; k <<= 1) m = fmaxf(m, __shfl_xor(m, k));
      float mn = fmaxf(mrow[r], m);
      sf[r] = __expf(mrow[r] - mn);
      mrow[r] = mn;
      pm[r] = mn;
      rs[r] = 0.f;
    }
#pragma unroll
    for (int n = 0; n < 4; ++n)
#pragma unroll
      for (int r = 0; r < 4; ++r) {
        float p = __expf(s[n][r] - pm[r]);
        s[n][r] = p;
        rs[r] += p;
      }
#pragma unroll
    for (int r = 0; r < 4; ++r) {
#pragma unroll
      for (int k = 1; k < 16; k <<= 1) rs[r] += __shfl_xor(rs[r], k);
      lrow[r] = lrow[r]*sf[r] + rs[r];
    }
#pragma unroll
    for (int nd = 0; nd < 8; ++nd)
#pragma unroll
      for (int r = 0; r < 4; ++r) o[nd][r] *= sf[r];
    // write P tile (bf16, swizzled)
#pragma unroll
    for (int n = 0; n < 4; ++n) {
      int pcol = n*16 + (lane & 15);
      int chunk = pcol >> 3;
#pragma unroll
      for (int r = 0; r < 4; ++r) {
        int prow = wv*16 + ((lane >> 4) << 2) + r;
        Ps[prow*64 + ((chunk ^ (prow & 7)) << 3) + (pcol & 7)] = f2bf(s[n][r]);
      }
    }
    __syncthreads();
#pragma unroll
    for (int ks = 0; ks < 2; ++ks) {
      int kb = ks*4 + (lane >> 4);
      int rp = wv*16 + (lane & 15);
      short8 pa = *(const short8*)(Ps + rp*64 + ((kb ^ (rp & 7)) << 3));
#pragma unroll
      for (int nd = 0; nd < 8; ++nd) {
        int rv2 = nd*16 + (lane & 15);
        short8 vb = *(const short8*)(Vs + rv2*64 + ((kb ^ (rv2 & 7)) << 3));
        o[nd] = mfma16(pa, vb, o[nd]);
      }
    }
  }
#pragma unroll
  for (int r = 0; r < 4; ++r) {
    float inv = 1.f / lrow[r];
    long token = (long)b*1024 + qt*64 + wv*16 + ((lane >> 4) << 2) + r;
#pragma unroll
    for (int nd = 0; nd < 8; ++nd) {
      long col = h*128 + nd*16 + (lane & 15);
      ctx[token*2048 + col] = f2bf(o[nd][r] * inv);
    }
  }
}

extern "C" void kernel_launch(void* const* d_in, const int* in_sizes, int n_in,
                              void* d_out, int out_size, void* d_ws, size_t ws_size,
                              hipStream_t stream) {
  (void)in_sizes; (void)n_in; (void)out_size; (void)ws_size;
  const float* hs        = (const float*)d_in[0];
  const float* qkv_w     = (const float*)d_in[2];
  const float* qkv_b     = (const float*)d_in[3];
  const float* dense_w   = (const float*)d_in[4];
  const float* dense_b   = (const float*)d_in[5];
  const float* w1        = (const float*)d_in[6];
  const float* b1        = (const float*)d_in[7];
  const float* w2        = (const float*)d_in[8];
  const float* b2        = (const float*)d_in[9];
  const float* ln_in_g   = (const float*)d_in[10];
  const float* ln_in_b   = (const float*)d_in[11];
  const float* ln_post_g = (const float*)d_in[12];
  const float* ln_post_b = (const float*)d_in[13];
  const float* ln_s1_g   = (const float*)d_in[14];
  const float* ln_s1_b   = (const float*)d_in[15];
  const float* ln_s2_g   = (const float*)d_in[16];
  const float* ln_s2_b   = (const float*)d_in[17];

  char* ws = (char*)d_ws;
  size_t off = 0;
  auto carve = [&](size_t bytes) { char* p = ws + off; off += (bytes + 255) & ~(size_t)255; return p; };
  unsigned short* wq    = (unsigned short*)carve(12582912ull*2);  // qkv_w bf16 (per layer)
  unsigned short* wd    = (unsigned short*)carve(4194304ull*2);   // dense_w bf16
  unsigned short* wm1   = (unsigned short*)carve(16777216ull*2);  // mlp_w1 bf16
  unsigned short* wm2   = (unsigned short*)carve(16777216ull*2);  // mlp_w2 bf16
  unsigned short* xbf   = (unsigned short*)carve(8388608ull*2);   // x (LN_in out) / y0 (LN_post out)
  unsigned short* qkvbf = (unsigned short*)carve(33554432ull*2);  // qkv activations / mlp1 out (t)
  unsigned short* vtbf  = (unsigned short*)carve(8388608ull*2);   // V transposed [bh][d][s]
  unsigned short* ctxbf = (unsigned short*)carve(8388608ull*2);   // attention context
  float*          gout  = (float*)carve(8388608ull*4);            // dense out / mlp2 out (fp32)
  float*          h2b   = (float*)carve(8388608ull*4);            // h2 residual
  float*          hbuf  = (float*)carve(8388608ull*4);            // inter-layer h

  for (int li = 0; li < 2; ++li) {
    const float* h_in = (li == 0) ? hs : hbuf;
    float* h_next = (li == 1) ? (float*)d_out : hbuf;

    cvt_kernel<<<1024, 256, 0, stream>>>(qkv_w   + (long)li*12582912, wq,  12582912/8);
    cvt_kernel<<<512,  256, 0, stream>>>(dense_w + (long)li*4194304,  wd,  4194304/8);
    cvt_kernel<<<1024, 256, 0, stream>>>(w1      + (long)li*16777216, wm1, 16777216/8);
    cvt_kernel<<<1024, 256, 0, stream>>>(w2      + (long)li*16777216, wm2, 16777216/8);

    ln_kernel<<<4096, 256, 0, stream>>>(h_in, ln_in_g + li*2048, ln_in_b + li*2048, xbf);

    gemm_bt<0,1><<<dim3(48,32), 256, 0, stream>>>(xbf, wq, qkv_b + li*6144, qkvbf, 4096, 6144, 2048);

    vtrans_kernel<<<dim3(32,4,64), 256, 0, stream>>>(qkvbf, vtbf);

    attn_kernel<<<dim3(16,64), 256, 0, stream>>>(qkvbf, vtbf, ctxbf);

    gemm_bt<0,0><<<dim3(16,32), 256, 0, stream>>>(ctxbf, wd, dense_b + li*2048, gout, 4096, 2048, 2048);

    fuse1_kernel<<<4096, 256, 0, stream>>>(gout, h_in,
                                           ln_s1_g + li*2048, ln_s1_b + li*2048,
                                           ln_post_g + li*2048, ln_post_b + li*2048,
                                           h2b, xbf);

    gemm_bt<1,1><<<dim3(64,32), 256, 0, stream>>>(xbf, wm1, b1 + li*8192, qkvbf, 4096, 8192, 2048);

    gemm_bt<0,0><<<dim3(16,32), 256, 0, stream>>>(qkvbf, wm2, b2 + li*2048, gout, 4096, 2048, 8192);

    fuse2_kernel<<<4096, 256, 0, stream>>>(gout, h2b, ln_s2_g + li*2048, ln_s2_b + li*2048, h_next);
  }
}